// Round 13
// baseline (290.127 us; speedup 1.0000x reference)
//
#include <hip/hip_runtime.h>
#include <math.h>

// ============ VERBATIM REVERT TO ROUND-9 KERNEL (passed, 289.9 us, absmax 0) ============
// r10-r12 stacked two sync-structure edits (minpass pm-LDS flush, cand_k ring-3) and hit a
// nondeterministic wrong-ids race that inspection could not localize. Per the two-lane
// discipline, sync-structure edits are new templates requiring isolated validation; this
// round restores the proven r9 artifact to re-establish a green baseline.

#define MROWS 16384   // B*N
#define DIMD  512
#define KCOD  8192
#define CAP   2097152u
// Scaled-domain margin: approxS = -2*8192*dot. 17.0 => 2.07e-3 unscaled (proven r7-r9).
#define MARGIN_S 17.0f

typedef __attribute__((ext_vector_type(4))) float f32x4;
typedef const __attribute__((address_space(1))) unsigned char glb_byte;
typedef __attribute__((address_space(3))) unsigned char lds_byte;

__device__ __forceinline__ void gload16(const void* g, void* l) {
    __builtin_amdgcn_global_load_lds((glb_byte*)g, (lds_byte*)l, 16, 0, 0);
}

// float -> OCP e4m3fn, RNE, saturate-to-448. Hand-rolled (deterministic). PROVEN r7-r9.
__device__ __forceinline__ unsigned f2e4m3(float f) {
    const unsigned b = __float_as_uint(f);
    const unsigned s = (b >> 24) & 0x80u;
    const unsigned ef = (b >> 23) & 0xFFu;
    const unsigned m = b & 0x7FFFFFu;
    if (ef == 0u) return s;
    const int e = (int)ef - 127;
    if (e >= -6) {
        unsigned q = m >> 20;
        const unsigned rem = m & 0xFFFFFu;
        q += (rem > 0x80000u) || (rem == 0x80000u && (q & 1u));
        unsigned te = (unsigned)(e + 7);
        if (q == 8u) { q = 0u; te += 1u; }
        if (te > 15u || (te == 15u && q == 7u)) return s | 0x7Eu;
        return s | (te << 3) | q;
    } else {
        const int sh = 20 + (-6 - e);
        if (sh > 31) return s;
        const unsigned m24 = 0x800000u | m;
        unsigned q = m24 >> sh;
        const unsigned rem = m24 & ((1u << sh) - 1u);
        const unsigned hlf = 1u << (sh - 1);
        q += (rem > hlf) || (rem == hlf && (q & 1u));
        if (q == 8u) return s | 0x08u;
        return s | q;
    }
}

// ---------------- ws layout (bytes); end 31818240 <= 38174976 (proven available) ----------------
#define OFF_A8      0u           // fp8 [16384][512] row-major            8MB
#define OFF_W8T     8388608u     // fp8 tiled [CT=64][half=2][kc=16][kg=4][c6=64][8]  4MB (scaled x8192)
#define OFF_XSQ     12582912u    // f32 [16384]
#define OFF_WSQ     12648448u    // f32 [8192]
#define OFF_THR     12681216u    // f32 [16384]  scaled rowmin+MARGIN_S
#define OFF_PM2     12746752u    // f32 [16384][128]   8MB (scaled per-(tile-half) minima)
#define OFF_RES     21135360u    // u64 [16384]
#define OFF_CTCNT   21266432u    // u32 [64]
#define OFF_GCNT    21266688u    // u32
#define OFF_CTROWS  21266944u    // u16 [64][16384]    2MB
#define OFF_LIST    23364096u    // u32 [CAP]          8MB
#define OFF_PARTIAL 31752704u    // f64 [8192]

// ===================== cvt: fp8 packing (A row-major; W scaled & pre-tiled) + exact sq-norms =====================
// Sum tree bit-identical to rounds 1-9 (passed absmax 0) — do not change the sum code.
__global__ __launch_bounds__(256) void cvt2_k(const float* __restrict__ A,
                                              const float* __restrict__ W,
                                              unsigned char* __restrict__ A8,
                                              unsigned char* __restrict__ W8T,
                                              float* __restrict__ xsq,
                                              float* __restrict__ wsq,
                                              unsigned int* __restrict__ ctcnt,
                                              unsigned int* __restrict__ gcount)
{
    if (blockIdx.x == 0 && threadIdx.x < 65) {     // zero per-call state (no re-poison between replays)
        if (threadIdx.x < 64) ctcnt[threadIdx.x] = 0u;
        else *gcount = 0u;
    }
    const int lane = threadIdx.x & 63;
    const int wid  = (blockIdx.x * blockDim.x + threadIdx.x) >> 6;
    const int nw   = (gridDim.x * blockDim.x) >> 6;
    for (int r = wid; r < MROWS + KCOD; r += nw) {
        const bool isA = (r < MROWS);
        const float4* src = (const float4*)(isA ? (A + (size_t)r * DIMD)
                                                : (W + (size_t)(r - MROWS) * DIMD));
        float4 v0 = src[lane];          // k = 4*lane .. +3
        float4 v1 = src[lane + 64];     // k = 256 + 4*lane .. +3
        float s = v0.x*v0.x + v0.y*v0.y + v0.z*v0.z + v0.w*v0.w
                + v1.x*v1.x + v1.y*v1.y + v1.z*v1.z + v1.w*v1.w;
        #pragma unroll
        for (int m = 1; m < 64; m <<= 1) s += __shfl_xor(s, m, 64);
        if (lane == 0) { if (isA) xsq[r] = s; else wsq[r - MROWS] = s; }

        if (isA) {
            const unsigned p0 = f2e4m3(v0.x) | (f2e4m3(v0.y) << 8) | (f2e4m3(v0.z) << 16) | (f2e4m3(v0.w) << 24);
            const unsigned p1 = f2e4m3(v1.x) | (f2e4m3(v1.y) << 8) | (f2e4m3(v1.z) << 16) | (f2e4m3(v1.w) << 24);
            *(unsigned*)(A8 + (size_t)r * DIMD + 4 * lane) = p0;
            *(unsigned*)(A8 + (size_t)r * DIMD + 256 + 4 * lane) = p1;
        } else {
            const int rw = r - MROWS;
            const int CT = rw >> 7, half = (rw >> 6) & 1, c6 = rw & 63;
            const unsigned p0 = f2e4m3(v0.x*8192.f) | (f2e4m3(v0.y*8192.f) << 8) | (f2e4m3(v0.z*8192.f) << 16) | (f2e4m3(v0.w*8192.f) << 24);
            const unsigned p1 = f2e4m3(v1.x*8192.f) | (f2e4m3(v1.y*8192.f) << 8) | (f2e4m3(v1.z*8192.f) << 16) | (f2e4m3(v1.w*8192.f) << 24);
            // layout [CT][half][kc][kg][c6][8]:
            // k0 = 4*lane: kc = lane>>3, kg = (lane>>1)&3, byte = 4*(lane&1); k1: kc = 8+(lane>>3)
            const size_t basea = (size_t)CT * 65536 + (size_t)half * 32768
                               + (size_t)((lane >> 1) & 3) * 512
                               + (size_t)c6 * 8 + 4 * (lane & 1);
            *(unsigned*)(W8T + basea + (size_t)(lane >> 3) * 2048) = p0;
            *(unsigned*)(W8T + basea + (size_t)(8 + (lane >> 3)) * 2048) = p1;
        }
    }
}

// ===================== min-pass fp8 GEMM: 4 waves/SIMD, shared B stream, round-robin staging =====================
// 1024 blocks = 128 row-tiles(128 rows) x 8 code-eighths(1024 codes); 256 thr = 4 waves (32 rows each).
// Chunk = 64 codes x 32 k = 2KB, linear in W8T. Wave (kc&3) stages chunk n+4 (2x gload16, G21-conformant),
// waits ITS OWN vmcnt(2), raw s_barrier publishes. 8-slot ring. acc chain (16 kc) identical to cand_k.
__global__ __launch_bounds__(256, 4) void minpass_k(
    const unsigned char* __restrict__ A8,
    const unsigned char* __restrict__ W8T,
    float* __restrict__ partmin2)
{
    __shared__ __align__(16) unsigned char Bs[8][2048];   // ring 16KB
    __shared__ __align__(16) unsigned char dmy[1024];     // tail dummy sink

    const int t    = threadIdx.x;
    const int lane = t & 63;
    const int wv   = t >> 6;                  // wave 0..3 = row quarter & staging slot owner
    const int rt   = (int)blockIdx.x & 127;   // row-tile (low bits -> XCD spreads rows, shares W8T)
    const int q    = (int)blockIdx.x >> 7;    // code eighth 0..7
    const int r0   = rt * 128;

    // A fragments: rows r0 + wv*32 + mi*16 + (lane&15), k = kc*32 + (lane>>4)*8
    long Areg[16][2];
    {
        const unsigned char* ab = A8 + (size_t)(r0 + wv * 32 + (lane & 15)) * DIMD + (lane >> 4) * 8;
        #pragma unroll
        for (int kc = 0; kc < 16; ++kc) {
            Areg[kc][0] = *(const long*)(ab + kc * 32);
            Areg[kc][1] = *(const long*)(ab + (size_t)16 * DIMD + kc * 32);
        }
    }

    const unsigned char* Wq = W8T + (size_t)q * 524288;   // 8 CTs x 64KB; chunk n at byte n*2048

    // prologue: wave wv stages chunk wv (chunks 0..3)
    {
        const unsigned char* s = Wq + wv * 2048 + lane * 16;
        gload16(s,        &Bs[wv][lane * 16]);
        gload16(s + 1024, &Bs[wv][1024 + lane * 16]);
    }

    const int qd = lane >> 4, c15 = lane & 15;
    const int pair = lane & 7;                               // which (mi,reg) this lane will keep
    // epilogue store row for this lane:
    const int erow = r0 + wv * 32 + (pair >> 2) * 16 + qd * 4 + (pair & 3);
    float* const estore = partmin2 + (size_t)erow * 128 + q * 16;

    for (int g = 0; g < 16; ++g) {            // 16 (CT,half) groups
        f32x4 acc[2][4];
        #pragma unroll
        for (int mi = 0; mi < 2; ++mi)
            #pragma unroll
            for (int ni = 0; ni < 4; ++ni) acc[mi][ni] = (f32x4){0.f, 0.f, 0.f, 0.f};

        #pragma unroll
        for (int kc = 0; kc < 16; ++kc) {
            const int n = g * 16 + kc;
            if ((kc & 3) == wv) {              // this wave stages chunk n+4
                const int np = n + 4;
                if (np < 256) {
                    const unsigned char* s = Wq + (size_t)np * 2048 + lane * 16;
                    gload16(s,        &Bs[np & 7][lane * 16]);
                    gload16(s + 1024, &Bs[np & 7][1024 + lane * 16]);
                } else {
                    gload16(Wq + lane * 16, &dmy[lane * 16]);
                    gload16(Wq + lane * 16, &dmy[lane * 16]);
                }
                asm volatile("s_waitcnt vmcnt(2)" ::: "memory");   // retire chunk n (own loads)
            }
            __builtin_amdgcn_s_barrier();                 // publish chunk n to all waves
            __builtin_amdgcn_sched_barrier(0);            // pin: no ds_read hoist above barrier

            const unsigned char* bb = &Bs[n & 7][qd * 512 + c15 * 8];
            long b[4];
            #pragma unroll
            for (int ni = 0; ni < 4; ++ni)
                b[ni] = *(const long*)(bb + ni * 128);
            #pragma unroll
            for (int mi = 0; mi < 2; ++mi)
                #pragma unroll
                for (int ni = 0; ni < 4; ++ni)
                    acc[mi][ni] = __builtin_amdgcn_mfma_f32_16x16x32_fp8_fp8(Areg[kc][mi], b[ni], acc[mi][ni], 0, 0, 0);
        }

        // epilogue (wave-local, no barrier): per-row min over this group's 64 codes -> direct global store
        float keep = 0.f;
        #pragma unroll
        for (int mi = 0; mi < 2; ++mi) {
            #pragma unroll
            for (int reg = 0; reg < 4; ++reg) {
                float mx = fmaxf(fmaxf(acc[mi][0][reg], acc[mi][1][reg]),
                                 fmaxf(acc[mi][2][reg], acc[mi][3][reg]));
                #pragma unroll
                for (int s = 1; s < 16; s <<= 1) mx = fmaxf(mx, __shfl_xor(mx, s, 64));
                if (pair == mi * 4 + reg) keep = mx;
            }
        }
        estore[g] = -2.0f * keep;   // column q*16+g; tile T = col>>1 (qualify's convention)
    }
}

// ===================== qualify (scaled domain): rowthr + block-aggregated bucket append =====================
__global__ __launch_bounds__(256) void qualify_k(const float* __restrict__ partmin2,
                                                 float* __restrict__ rowthr,
                                                 unsigned int* __restrict__ ctcnt,
                                                 unsigned short* __restrict__ ctrows,
                                                 unsigned long long* __restrict__ res)
{
    __shared__ unsigned cntA[64], baseL[64], cntB[64];
    const int t = threadIdx.x;
    const int r = blockIdx.x * 256 + t;   // grid 64

    if (t < 64) { cntA[t] = 0u; cntB[t] = 0u; }

    const f32x4* p = (const f32x4*)(partmin2 + (size_t)r * 128);
    float m = INFINITY;
    for (int i = 0; i < 32; ++i) {
        f32x4 x = p[i];
        m = fminf(fminf(fminf(x[0], x[1]), fminf(x[2], x[3])), m);
    }
    const float thr = m + MARGIN_S;
    rowthr[r] = thr;
    res[r] = ~0ull;

    unsigned long long qm = 0ull;
    for (int i = 0; i < 32; ++i) {
        f32x4 x = p[i];
        if (fminf(x[0], x[1]) <= thr) qm |= 1ull << (2 * i);
        if (fminf(x[2], x[3]) <= thr) qm |= 1ull << (2 * i + 1);
    }
    __syncthreads();
    unsigned long long mm = qm;
    while (mm) {
        const int tile = __ffsll((long long)mm) - 1;
        mm &= mm - 1;
        atomicAdd(&cntA[tile], 1u);
    }
    __syncthreads();
    if (t < 64) baseL[t] = cntA[t] ? atomicAdd(&ctcnt[t], cntA[t]) : 0u;
    __syncthreads();
    mm = qm;
    while (mm) {
        const int tile = __ffsll((long long)mm) - 1;
        mm &= mm - 1;
        const unsigned pos = baseL[tile] + atomicAdd(&cntB[tile], 1u);
        ctrows[tile * 16384 + pos] = (unsigned short)r;
    }
}

// ===================== sparse candidate GEMM (fp8; bit-identical accumulation chain vs minpass) =====================
__global__ __launch_bounds__(256) void cand_k(
    const unsigned char* __restrict__ A8,
    const unsigned char* __restrict__ W8T,
    const float* __restrict__ rowthr,
    const unsigned int* __restrict__ ctcnt,
    const unsigned short* __restrict__ ctrows,
    unsigned int* __restrict__ list,
    unsigned int* __restrict__ gcount)
{
    __shared__ __align__(16) unsigned char As[2][4096];   // [row][32B] row-major
    __shared__ __align__(16) unsigned char Bs[2][4096];   // [half][kg][c6][8]
    __shared__ int ids_lds[128];
    __shared__ float thr_lds[128];
    __shared__ unsigned wtot[4];
    __shared__ unsigned gb_lds;

    const int T = blockIdx.x;                  // tile 0..63, codes T*128..+127
    unsigned n = ctcnt[T]; if (n > 16384u) n = 16384u;
    const unsigned base = blockIdx.y * 128;
    if (base >= n) return;

    const int t    = threadIdx.x;
    const int lane = t & 63;
    const int w    = t >> 6;
    const int wm   = w >> 1, wn = w & 1;
    const int c0   = T * 128;

    if (t < 128) {
        const int g = (base + t < n) ? (int)ctrows[T * 16384 + base + t] : -1;
        ids_lds[t] = (g < 0) ? 0 : g;
        thr_lds[t] = (g < 0) ? -INFINITY : rowthr[g];
    }
    __syncthreads();

    const unsigned char* bbase = W8T + (size_t)T * 65536;   // [half][kc][kg][c6][8]
    const int srow = t >> 1, skh = (t & 1) * 16;
    const int bh = t >> 7, bt = t & 127;                    // staging: half, thread-in-half

    gload16(A8 + (size_t)ids_lds[srow] * DIMD + skh, &As[0][t * 16]);
    gload16(bbase + (size_t)bh * 32768 + bt * 16, &Bs[0][t * 16]);

    f32x4 acc[4][4];
    #pragma unroll
    for (int mi = 0; mi < 4; ++mi)
        #pragma unroll
        for (int ni = 0; ni < 4; ++ni) acc[mi][ni] = (f32x4){0.f, 0.f, 0.f, 0.f};

    int cur = 0;
    for (int kc = 0; kc < 16; ++kc) {
        __syncthreads();
        if (kc + 1 < 16) {
            const int nb = cur ^ 1;
            gload16(A8 + (size_t)ids_lds[srow] * DIMD + (kc + 1) * 32 + skh, &As[nb][t * 16]);
            gload16(bbase + (size_t)bh * 32768 + (size_t)(kc + 1) * 2048 + bt * 16, &Bs[nb][t * 16]);
        }
        long a[4], b[4];
        #pragma unroll
        for (int mi = 0; mi < 4; ++mi)
            a[mi] = *(const long*)&As[cur][(wm * 64 + mi * 16 + (lane & 15)) * 32 + (lane >> 4) * 8];
        #pragma unroll
        for (int ni = 0; ni < 4; ++ni)
            b[ni] = *(const long*)&Bs[cur][wn * 2048 + (lane >> 4) * 512 + (ni * 16 + (lane & 15)) * 8];
        #pragma unroll
        for (int mi = 0; mi < 4; ++mi)
            #pragma unroll
            for (int ni = 0; ni < 4; ++ni)
                acc[mi][ni] = __builtin_amdgcn_mfma_f32_16x16x32_fp8_fp8(a[mi], b[ni], acc[mi][ni], 0, 0, 0);
        __syncthreads();
        cur ^= 1;
    }

    // phase A: count hits (approxS = fl(-2*accS), bit-consistent with minpass)
    unsigned nh = 0;
    #pragma unroll
    for (int mi = 0; mi < 4; ++mi)
        #pragma unroll
        for (int reg = 0; reg < 4; ++reg) {
            const float thr = thr_lds[wm * 64 + mi * 16 + (lane >> 4) * 4 + reg];
            #pragma unroll
            for (int ni = 0; ni < 4; ++ni)
                if (-2.0f * acc[mi][ni][reg] <= thr) ++nh;
        }

    unsigned pfx = nh;
    #pragma unroll
    for (int s = 1; s < 64; s <<= 1) {
        unsigned v = __shfl_up(pfx, s, 64);
        if (lane >= s) pfx += v;
    }
    if (lane == 63) wtot[w] = pfx;
    __syncthreads();
    if (t == 0) {
        const unsigned tot = wtot[0] + wtot[1] + wtot[2] + wtot[3];
        gb_lds = tot ? atomicAdd(gcount, tot) : 0u;
    }
    __syncthreads();
    unsigned wb = 0;
    #pragma unroll
    for (int i = 0; i < 4; ++i) if (i < w) wb += wtot[i];
    unsigned myoff = gb_lds + wb + pfx - nh;   // exclusive offset

    #pragma unroll
    for (int mi = 0; mi < 4; ++mi)
        #pragma unroll
        for (int reg = 0; reg < 4; ++reg) {
            const int row_l = wm * 64 + mi * 16 + (lane >> 4) * 4 + reg;
            const float thr = thr_lds[row_l];
            #pragma unroll
            for (int ni = 0; ni < 4; ++ni) {
                if (-2.0f * acc[mi][ni][reg] <= thr) {
                    const unsigned k = c0 + wn * 64 + ni * 16 + (lane & 15);
                    if (myoff < CAP)
                        list[myoff] = ((unsigned)ids_lds[row_l] << 13) | k;
                    ++myoff;
                }
            }
        }
}

// ===================== fp64-exact refine: 16-lane groups (bit-exact carryover) =====================
__global__ __launch_bounds__(256) void refine_k(const float* __restrict__ A,
                                                const float* __restrict__ W,
                                                const float* __restrict__ xsq,
                                                const float* __restrict__ wsq,
                                                const unsigned* __restrict__ list,
                                                const unsigned* __restrict__ gcount,
                                                unsigned long long* __restrict__ res)
{
    const int gl  = threadIdx.x & 15;
    const int gid = (blockIdx.x * 256 + threadIdx.x) >> 4;
    const int ngr = (gridDim.x * 256) >> 4;
    unsigned n = *gcount;
    if (n > CAP) n = CAP;
    for (unsigned i = gid; i < n; i += ngr) {
        const unsigned pk = list[i];
        const unsigned row = pk >> 13, k = pk & 8191u;
        const float4* xp = (const float4*)(A + (size_t)row * DIMD);
        const float4* wp = (const float4*)(W + (size_t)k * DIMD);
        double s = 0.0;
        #pragma unroll
        for (int j = 0; j < 8; ++j) {
            const float4 x = xp[j * 16 + gl];
            const float4 w = wp[j * 16 + gl];
            s += (double)x.x * w.x + (double)x.y * w.y
               + (double)x.z * w.z + (double)x.w * w.w;
        }
        #pragma unroll
        for (int m = 1; m < 16; m <<= 1) s += __shfl_xor(s, m, 64);
        if (gl == 0) {
            const float Df = (float)s;
            const float dist = (xsq[row] + wsq[k]) - 2.0f * Df;
            const unsigned long long p =
                ((unsigned long long)__float_as_uint(dist) << 32) | (unsigned long long)k;
            atomicMin(res + row, p);
        }
    }
}

// ===================== outputs: gather (+ids, finish fused) + losses =====================
__global__ __launch_bounds__(256) void gather_k(const float* __restrict__ A,
                                                const float* __restrict__ W,
                                                const unsigned long long* __restrict__ res,
                                                float* __restrict__ out_zq,
                                                float* __restrict__ out_ids,
                                                double* __restrict__ partial)
{
    __shared__ double wsum[4];
    const int t   = threadIdx.x;
    const int row = blockIdx.x * 2 + (t >> 7);
    const int col = t & 127;
    const int id  = (int)(res[row] & 8191ull);
    if ((t & 127) == 0) out_ids[row] = (float)id;
    const float4 ze = ((const float4*)(A + (size_t)row * DIMD))[col];
    const float4 zq = ((const float4*)(W + (size_t)id  * DIMD))[col];
    float4 o;
    o.x = ze.x + (zq.x - ze.x);
    o.y = ze.y + (zq.y - ze.y);
    o.z = ze.z + (zq.z - ze.z);
    o.w = ze.w + (zq.w - ze.w);
    ((float4*)(out_zq + (size_t)row * DIMD))[col] = o;
    const float dx = zq.x - ze.x, dy = zq.y - ze.y, dz = zq.z - ze.z, dw = zq.w - ze.w;
    double s = (double)dx*dx + (double)dy*dy + (double)dz*dz + (double)dw*dw;
    #pragma unroll
    for (int m = 1; m < 64; m <<= 1) s += __shfl_xor(s, m, 64);
    if ((t & 63) == 0) wsum[t >> 6] = s;
    __syncthreads();
    if (t == 0) partial[blockIdx.x] = (wsum[0] + wsum[1]) + (wsum[2] + wsum[3]);
}

__global__ __launch_bounds__(256) void fin_k(const double* __restrict__ partial,
                                             float* __restrict__ outs)
{
    __shared__ double wsum[4];
    const int t = threadIdx.x;
    double s = 0.0;
    for (int i = 0; i < 32; ++i) s += partial[t + 256 * i];
    #pragma unroll
    for (int m = 1; m < 64; m <<= 1) s += __shfl_xor(s, m, 64);
    if ((t & 63) == 0) wsum[t >> 6] = s;
    __syncthreads();
    if (t == 0) {
        const double tot = (wsum[0] + wsum[1]) + (wsum[2] + wsum[3]);
        const double mse = tot / (double)((size_t)MROWS * DIMD);
        const float mf = (float)mse;
        const float vq = (float)(mse * 1.25);
        outs[0] = vq; outs[1] = mf; outs[2] = mf; outs[3] = 0.0f; outs[4] = vq;
    }
}

// ===================== launch =====================

extern "C" void kernel_launch(void* const* d_in, const int* in_sizes, int n_in,
                              void* d_out, int out_size, void* d_ws, size_t ws_size,
                              hipStream_t stream)
{
    const float* A = (const float*)d_in[0];
    const float* W = (const float*)d_in[1];

    char* ws = (char*)d_ws;
    unsigned char* A8  = (unsigned char*)(ws + OFF_A8);
    unsigned char* W8T = (unsigned char*)(ws + OFF_W8T);
    float*  xsq     = (float*)(ws + OFF_XSQ);
    float*  wsq     = (float*)(ws + OFF_WSQ);
    float*  rowthr  = (float*)(ws + OFF_THR);
    float*  partmin2= (float*)(ws + OFF_PM2);
    unsigned long long* res = (unsigned long long*)(ws + OFF_RES);
    unsigned int* ctcnt     = (unsigned int*)(ws + OFF_CTCNT);
    unsigned int* gcount    = (unsigned int*)(ws + OFF_GCNT);
    unsigned short* ctrows  = (unsigned short*)(ws + OFF_CTROWS);
    unsigned int* list      = (unsigned int*)(ws + OFF_LIST);
    double* partial = (double*)(ws + OFF_PARTIAL);

    float* out_zq  = (float*)d_out;
    float* out_ids = out_zq + (size_t)MROWS * DIMD;
    float* out_sc  = out_ids + MROWS;

    cvt2_k<<<512, 256, 0, stream>>>(A, W, A8, W8T, xsq, wsq, ctcnt, gcount);
    minpass_k<<<1024, 256, 0, stream>>>(A8, W8T, partmin2);
    qualify_k<<<64, 256, 0, stream>>>(partmin2, rowthr, ctcnt, ctrows, res);
    cand_k<<<dim3(64, 128), 256, 0, stream>>>(A8, W8T, rowthr, ctcnt, ctrows, list, gcount);
    refine_k<<<1024, 256, 0, stream>>>(A, W, xsq, wsq, list, gcount, res);
    gather_k<<<8192, 256, 0, stream>>>(A, W, res, out_zq, out_ids, partial);
    fin_k<<<1, 256, 0, stream>>>(partial, out_sc);
}

// Round 14
// 278.840 us; speedup vs baseline: 1.0405x; 1.0405x over previous
//
#include <hip/hip_runtime.h>
#include <math.h>

// ============ ROUND-13 PROVEN KERNEL (passed, 290 us, absmax 0) + launch-config-only tuning ============
// r14 delta vs r13: cvt2_k grid 512->2048 (was 2 blocks/CU for a VALU-heavy kernel),
// refine_k grid 1024->2048 (halves serial iterations per wave-group). NO code changes.
// The r10-r12 sync-structure edits (minpass pm-LDS flush, cand ring-3) remain quarantined:
// they produced a nondeterministic wrong-ids race not localizable by inspection.

#define MROWS 16384   // B*N
#define DIMD  512
#define KCOD  8192
#define CAP   2097152u
// Scaled-domain margin: approxS = -2*8192*dot. 17.0 => 2.07e-3 unscaled (proven r7-r9, r13).
#define MARGIN_S 17.0f

typedef __attribute__((ext_vector_type(4))) float f32x4;
typedef const __attribute__((address_space(1))) unsigned char glb_byte;
typedef __attribute__((address_space(3))) unsigned char lds_byte;

__device__ __forceinline__ void gload16(const void* g, void* l) {
    __builtin_amdgcn_global_load_lds((glb_byte*)g, (lds_byte*)l, 16, 0, 0);
}

// float -> OCP e4m3fn, RNE, saturate-to-448. Hand-rolled (deterministic). PROVEN r7-r9, r13.
__device__ __forceinline__ unsigned f2e4m3(float f) {
    const unsigned b = __float_as_uint(f);
    const unsigned s = (b >> 24) & 0x80u;
    const unsigned ef = (b >> 23) & 0xFFu;
    const unsigned m = b & 0x7FFFFFu;
    if (ef == 0u) return s;
    const int e = (int)ef - 127;
    if (e >= -6) {
        unsigned q = m >> 20;
        const unsigned rem = m & 0xFFFFFu;
        q += (rem > 0x80000u) || (rem == 0x80000u && (q & 1u));
        unsigned te = (unsigned)(e + 7);
        if (q == 8u) { q = 0u; te += 1u; }
        if (te > 15u || (te == 15u && q == 7u)) return s | 0x7Eu;
        return s | (te << 3) | q;
    } else {
        const int sh = 20 + (-6 - e);
        if (sh > 31) return s;
        const unsigned m24 = 0x800000u | m;
        unsigned q = m24 >> sh;
        const unsigned rem = m24 & ((1u << sh) - 1u);
        const unsigned hlf = 1u << (sh - 1);
        q += (rem > hlf) || (rem == hlf && (q & 1u));
        if (q == 8u) return s | 0x08u;
        return s | q;
    }
}

// ---------------- ws layout (bytes); end 31818240 <= 38174976 (proven available) ----------------
#define OFF_A8      0u           // fp8 [16384][512] row-major            8MB
#define OFF_W8T     8388608u     // fp8 tiled [CT=64][half=2][kc=16][kg=4][c6=64][8]  4MB (scaled x8192)
#define OFF_XSQ     12582912u    // f32 [16384]
#define OFF_WSQ     12648448u    // f32 [8192]
#define OFF_THR     12681216u    // f32 [16384]  scaled rowmin+MARGIN_S
#define OFF_PM2     12746752u    // f32 [16384][128]   8MB (scaled per-(tile-half) minima)
#define OFF_RES     21135360u    // u64 [16384]
#define OFF_CTCNT   21266432u    // u32 [64]
#define OFF_GCNT    21266688u    // u32
#define OFF_CTROWS  21266944u    // u16 [64][16384]    2MB
#define OFF_LIST    23364096u    // u32 [CAP]          8MB
#define OFF_PARTIAL 31752704u    // f64 [8192]

// ===================== cvt: fp8 packing (A row-major; W scaled & pre-tiled) + exact sq-norms =====================
// Sum tree bit-identical to rounds 1-13 (passed absmax 0) — do not change the sum code.
__global__ __launch_bounds__(256) void cvt2_k(const float* __restrict__ A,
                                              const float* __restrict__ W,
                                              unsigned char* __restrict__ A8,
                                              unsigned char* __restrict__ W8T,
                                              float* __restrict__ xsq,
                                              float* __restrict__ wsq,
                                              unsigned int* __restrict__ ctcnt,
                                              unsigned int* __restrict__ gcount)
{
    if (blockIdx.x == 0 && threadIdx.x < 65) {     // zero per-call state (no re-poison between replays)
        if (threadIdx.x < 64) ctcnt[threadIdx.x] = 0u;
        else *gcount = 0u;
    }
    const int lane = threadIdx.x & 63;
    const int wid  = (blockIdx.x * blockDim.x + threadIdx.x) >> 6;
    const int nw   = (gridDim.x * blockDim.x) >> 6;
    for (int r = wid; r < MROWS + KCOD; r += nw) {
        const bool isA = (r < MROWS);
        const float4* src = (const float4*)(isA ? (A + (size_t)r * DIMD)
                                                : (W + (size_t)(r - MROWS) * DIMD));
        float4 v0 = src[lane];          // k = 4*lane .. +3
        float4 v1 = src[lane + 64];     // k = 256 + 4*lane .. +3
        float s = v0.x*v0.x + v0.y*v0.y + v0.z*v0.z + v0.w*v0.w
                + v1.x*v1.x + v1.y*v1.y + v1.z*v1.z + v1.w*v1.w;
        #pragma unroll
        for (int m = 1; m < 64; m <<= 1) s += __shfl_xor(s, m, 64);
        if (lane == 0) { if (isA) xsq[r] = s; else wsq[r - MROWS] = s; }

        if (isA) {
            const unsigned p0 = f2e4m3(v0.x) | (f2e4m3(v0.y) << 8) | (f2e4m3(v0.z) << 16) | (f2e4m3(v0.w) << 24);
            const unsigned p1 = f2e4m3(v1.x) | (f2e4m3(v1.y) << 8) | (f2e4m3(v1.z) << 16) | (f2e4m3(v1.w) << 24);
            *(unsigned*)(A8 + (size_t)r * DIMD + 4 * lane) = p0;
            *(unsigned*)(A8 + (size_t)r * DIMD + 256 + 4 * lane) = p1;
        } else {
            const int rw = r - MROWS;
            const int CT = rw >> 7, half = (rw >> 6) & 1, c6 = rw & 63;
            const unsigned p0 = f2e4m3(v0.x*8192.f) | (f2e4m3(v0.y*8192.f) << 8) | (f2e4m3(v0.z*8192.f) << 16) | (f2e4m3(v0.w*8192.f) << 24);
            const unsigned p1 = f2e4m3(v1.x*8192.f) | (f2e4m3(v1.y*8192.f) << 8) | (f2e4m3(v1.z*8192.f) << 16) | (f2e4m3(v1.w*8192.f) << 24);
            // layout [CT][half][kc][kg][c6][8]:
            // k0 = 4*lane: kc = lane>>3, kg = (lane>>1)&3, byte = 4*(lane&1); k1: kc = 8+(lane>>3)
            const size_t basea = (size_t)CT * 65536 + (size_t)half * 32768
                               + (size_t)((lane >> 1) & 3) * 512
                               + (size_t)c6 * 8 + 4 * (lane & 1);
            *(unsigned*)(W8T + basea + (size_t)(lane >> 3) * 2048) = p0;
            *(unsigned*)(W8T + basea + (size_t)(8 + (lane >> 3)) * 2048) = p1;
        }
    }
}

// ===================== min-pass fp8 GEMM: 4 waves/SIMD, shared B stream, round-robin staging =====================
// 1024 blocks = 128 row-tiles(128 rows) x 8 code-eighths(1024 codes); 256 thr = 4 waves (32 rows each).
// Chunk = 64 codes x 32 k = 2KB, linear in W8T. Wave (kc&3) stages chunk n+4 (2x gload16, G21-conformant),
// waits ITS OWN vmcnt(2), raw s_barrier publishes. 8-slot ring. acc chain (16 kc) identical to cand_k.
__global__ __launch_bounds__(256, 4) void minpass_k(
    const unsigned char* __restrict__ A8,
    const unsigned char* __restrict__ W8T,
    float* __restrict__ partmin2)
{
    __shared__ __align__(16) unsigned char Bs[8][2048];   // ring 16KB
    __shared__ __align__(16) unsigned char dmy[1024];     // tail dummy sink

    const int t    = threadIdx.x;
    const int lane = t & 63;
    const int wv   = t >> 6;                  // wave 0..3 = row quarter & staging slot owner
    const int rt   = (int)blockIdx.x & 127;   // row-tile (low bits -> XCD spreads rows, shares W8T)
    const int q    = (int)blockIdx.x >> 7;    // code eighth 0..7
    const int r0   = rt * 128;

    // A fragments: rows r0 + wv*32 + mi*16 + (lane&15), k = kc*32 + (lane>>4)*8
    long Areg[16][2];
    {
        const unsigned char* ab = A8 + (size_t)(r0 + wv * 32 + (lane & 15)) * DIMD + (lane >> 4) * 8;
        #pragma unroll
        for (int kc = 0; kc < 16; ++kc) {
            Areg[kc][0] = *(const long*)(ab + kc * 32);
            Areg[kc][1] = *(const long*)(ab + (size_t)16 * DIMD + kc * 32);
        }
    }

    const unsigned char* Wq = W8T + (size_t)q * 524288;   // 8 CTs x 64KB; chunk n at byte n*2048

    // prologue: wave wv stages chunk wv (chunks 0..3)
    {
        const unsigned char* s = Wq + wv * 2048 + lane * 16;
        gload16(s,        &Bs[wv][lane * 16]);
        gload16(s + 1024, &Bs[wv][1024 + lane * 16]);
    }

    const int qd = lane >> 4, c15 = lane & 15;
    const int pair = lane & 7;                               // which (mi,reg) this lane will keep
    // epilogue store row for this lane:
    const int erow = r0 + wv * 32 + (pair >> 2) * 16 + qd * 4 + (pair & 3);
    float* const estore = partmin2 + (size_t)erow * 128 + q * 16;

    for (int g = 0; g < 16; ++g) {            // 16 (CT,half) groups
        f32x4 acc[2][4];
        #pragma unroll
        for (int mi = 0; mi < 2; ++mi)
            #pragma unroll
            for (int ni = 0; ni < 4; ++ni) acc[mi][ni] = (f32x4){0.f, 0.f, 0.f, 0.f};

        #pragma unroll
        for (int kc = 0; kc < 16; ++kc) {
            const int n = g * 16 + kc;
            if ((kc & 3) == wv) {              // this wave stages chunk n+4
                const int np = n + 4;
                if (np < 256) {
                    const unsigned char* s = Wq + (size_t)np * 2048 + lane * 16;
                    gload16(s,        &Bs[np & 7][lane * 16]);
                    gload16(s + 1024, &Bs[np & 7][1024 + lane * 16]);
                } else {
                    gload16(Wq + lane * 16, &dmy[lane * 16]);
                    gload16(Wq + lane * 16, &dmy[lane * 16]);
                }
                asm volatile("s_waitcnt vmcnt(2)" ::: "memory");   // retire chunk n (own loads)
            }
            __builtin_amdgcn_s_barrier();                 // publish chunk n to all waves
            __builtin_amdgcn_sched_barrier(0);            // pin: no ds_read hoist above barrier

            const unsigned char* bb = &Bs[n & 7][qd * 512 + c15 * 8];
            long b[4];
            #pragma unroll
            for (int ni = 0; ni < 4; ++ni)
                b[ni] = *(const long*)(bb + ni * 128);
            #pragma unroll
            for (int mi = 0; mi < 2; ++mi)
                #pragma unroll
                for (int ni = 0; ni < 4; ++ni)
                    acc[mi][ni] = __builtin_amdgcn_mfma_f32_16x16x32_fp8_fp8(Areg[kc][mi], b[ni], acc[mi][ni], 0, 0, 0);
        }

        // epilogue (wave-local, no barrier): per-row min over this group's 64 codes -> direct global store
        float keep = 0.f;
        #pragma unroll
        for (int mi = 0; mi < 2; ++mi) {
            #pragma unroll
            for (int reg = 0; reg < 4; ++reg) {
                float mx = fmaxf(fmaxf(acc[mi][0][reg], acc[mi][1][reg]),
                                 fmaxf(acc[mi][2][reg], acc[mi][3][reg]));
                #pragma unroll
                for (int s = 1; s < 16; s <<= 1) mx = fmaxf(mx, __shfl_xor(mx, s, 64));
                if (pair == mi * 4 + reg) keep = mx;
            }
        }
        estore[g] = -2.0f * keep;   // column q*16+g; tile T = col>>1 (qualify's convention)
    }
}

// ===================== qualify (scaled domain): rowthr + block-aggregated bucket append =====================
__global__ __launch_bounds__(256) void qualify_k(const float* __restrict__ partmin2,
                                                 float* __restrict__ rowthr,
                                                 unsigned int* __restrict__ ctcnt,
                                                 unsigned short* __restrict__ ctrows,
                                                 unsigned long long* __restrict__ res)
{
    __shared__ unsigned cntA[64], baseL[64], cntB[64];
    const int t = threadIdx.x;
    const int r = blockIdx.x * 256 + t;   // grid 64

    if (t < 64) { cntA[t] = 0u; cntB[t] = 0u; }

    const f32x4* p = (const f32x4*)(partmin2 + (size_t)r * 128);
    float m = INFINITY;
    for (int i = 0; i < 32; ++i) {
        f32x4 x = p[i];
        m = fminf(fminf(fminf(x[0], x[1]), fminf(x[2], x[3])), m);
    }
    const float thr = m + MARGIN_S;
    rowthr[r] = thr;
    res[r] = ~0ull;

    unsigned long long qm = 0ull;
    for (int i = 0; i < 32; ++i) {
        f32x4 x = p[i];
        if (fminf(x[0], x[1]) <= thr) qm |= 1ull << (2 * i);
        if (fminf(x[2], x[3]) <= thr) qm |= 1ull << (2 * i + 1);
    }
    __syncthreads();
    unsigned long long mm = qm;
    while (mm) {
        const int tile = __ffsll((long long)mm) - 1;
        mm &= mm - 1;
        atomicAdd(&cntA[tile], 1u);
    }
    __syncthreads();
    if (t < 64) baseL[t] = cntA[t] ? atomicAdd(&ctcnt[t], cntA[t]) : 0u;
    __syncthreads();
    mm = qm;
    while (mm) {
        const int tile = __ffsll((long long)mm) - 1;
        mm &= mm - 1;
        const unsigned pos = baseL[tile] + atomicAdd(&cntB[tile], 1u);
        ctrows[tile * 16384 + pos] = (unsigned short)r;
    }
}

// ===================== sparse candidate GEMM (fp8; bit-identical accumulation chain vs minpass) =====================
__global__ __launch_bounds__(256) void cand_k(
    const unsigned char* __restrict__ A8,
    const unsigned char* __restrict__ W8T,
    const float* __restrict__ rowthr,
    const unsigned int* __restrict__ ctcnt,
    const unsigned short* __restrict__ ctrows,
    unsigned int* __restrict__ list,
    unsigned int* __restrict__ gcount)
{
    __shared__ __align__(16) unsigned char As[2][4096];   // [row][32B] row-major
    __shared__ __align__(16) unsigned char Bs[2][4096];   // [half][kg][c6][8]
    __shared__ int ids_lds[128];
    __shared__ float thr_lds[128];
    __shared__ unsigned wtot[4];
    __shared__ unsigned gb_lds;

    const int T = blockIdx.x;                  // tile 0..63, codes T*128..+127
    unsigned n = ctcnt[T]; if (n > 16384u) n = 16384u;
    const unsigned base = blockIdx.y * 128;
    if (base >= n) return;

    const int t    = threadIdx.x;
    const int lane = t & 63;
    const int w    = t >> 6;
    const int wm   = w >> 1, wn = w & 1;
    const int c0   = T * 128;

    if (t < 128) {
        const int g = (base + t < n) ? (int)ctrows[T * 16384 + base + t] : -1;
        ids_lds[t] = (g < 0) ? 0 : g;
        thr_lds[t] = (g < 0) ? -INFINITY : rowthr[g];
    }
    __syncthreads();

    const unsigned char* bbase = W8T + (size_t)T * 65536;   // [half][kc][kg][c6][8]
    const int srow = t >> 1, skh = (t & 1) * 16;
    const int bh = t >> 7, bt = t & 127;                    // staging: half, thread-in-half

    gload16(A8 + (size_t)ids_lds[srow] * DIMD + skh, &As[0][t * 16]);
    gload16(bbase + (size_t)bh * 32768 + bt * 16, &Bs[0][t * 16]);

    f32x4 acc[4][4];
    #pragma unroll
    for (int mi = 0; mi < 4; ++mi)
        #pragma unroll
        for (int ni = 0; ni < 4; ++ni) acc[mi][ni] = (f32x4){0.f, 0.f, 0.f, 0.f};

    int cur = 0;
    for (int kc = 0; kc < 16; ++kc) {
        __syncthreads();
        if (kc + 1 < 16) {
            const int nb = cur ^ 1;
            gload16(A8 + (size_t)ids_lds[srow] * DIMD + (kc + 1) * 32 + skh, &As[nb][t * 16]);
            gload16(bbase + (size_t)bh * 32768 + (size_t)(kc + 1) * 2048 + bt * 16, &Bs[nb][t * 16]);
        }
        long a[4], b[4];
        #pragma unroll
        for (int mi = 0; mi < 4; ++mi)
            a[mi] = *(const long*)&As[cur][(wm * 64 + mi * 16 + (lane & 15)) * 32 + (lane >> 4) * 8];
        #pragma unroll
        for (int ni = 0; ni < 4; ++ni)
            b[ni] = *(const long*)&Bs[cur][wn * 2048 + (lane >> 4) * 512 + (ni * 16 + (lane & 15)) * 8];
        #pragma unroll
        for (int mi = 0; mi < 4; ++mi)
            #pragma unroll
            for (int ni = 0; ni < 4; ++ni)
                acc[mi][ni] = __builtin_amdgcn_mfma_f32_16x16x32_fp8_fp8(a[mi], b[ni], acc[mi][ni], 0, 0, 0);
        __syncthreads();
        cur ^= 1;
    }

    // phase A: count hits (approxS = fl(-2*accS), bit-consistent with minpass)
    unsigned nh = 0;
    #pragma unroll
    for (int mi = 0; mi < 4; ++mi)
        #pragma unroll
        for (int reg = 0; reg < 4; ++reg) {
            const float thr = thr_lds[wm * 64 + mi * 16 + (lane >> 4) * 4 + reg];
            #pragma unroll
            for (int ni = 0; ni < 4; ++ni)
                if (-2.0f * acc[mi][ni][reg] <= thr) ++nh;
        }

    unsigned pfx = nh;
    #pragma unroll
    for (int s = 1; s < 64; s <<= 1) {
        unsigned v = __shfl_up(pfx, s, 64);
        if (lane >= s) pfx += v;
    }
    if (lane == 63) wtot[w] = pfx;
    __syncthreads();
    if (t == 0) {
        const unsigned tot = wtot[0] + wtot[1] + wtot[2] + wtot[3];
        gb_lds = tot ? atomicAdd(gcount, tot) : 0u;
    }
    __syncthreads();
    unsigned wb = 0;
    #pragma unroll
    for (int i = 0; i < 4; ++i) if (i < w) wb += wtot[i];
    unsigned myoff = gb_lds + wb + pfx - nh;   // exclusive offset

    #pragma unroll
    for (int mi = 0; mi < 4; ++mi)
        #pragma unroll
        for (int reg = 0; reg < 4; ++reg) {
            const int row_l = wm * 64 + mi * 16 + (lane >> 4) * 4 + reg;
            const float thr = thr_lds[row_l];
            #pragma unroll
            for (int ni = 0; ni < 4; ++ni) {
                if (-2.0f * acc[mi][ni][reg] <= thr) {
                    const unsigned k = c0 + wn * 64 + ni * 16 + (lane & 15);
                    if (myoff < CAP)
                        list[myoff] = ((unsigned)ids_lds[row_l] << 13) | k;
                    ++myoff;
                }
            }
        }
}

// ===================== fp64-exact refine: 16-lane groups (bit-exact carryover) =====================
__global__ __launch_bounds__(256) void refine_k(const float* __restrict__ A,
                                                const float* __restrict__ W,
                                                const float* __restrict__ xsq,
                                                const float* __restrict__ wsq,
                                                const unsigned* __restrict__ list,
                                                const unsigned* __restrict__ gcount,
                                                unsigned long long* __restrict__ res)
{
    const int gl  = threadIdx.x & 15;
    const int gid = (blockIdx.x * 256 + threadIdx.x) >> 4;
    const int ngr = (gridDim.x * 256) >> 4;
    unsigned n = *gcount;
    if (n > CAP) n = CAP;
    for (unsigned i = gid; i < n; i += ngr) {
        const unsigned pk = list[i];
        const unsigned row = pk >> 13, k = pk & 8191u;
        const float4* xp = (const float4*)(A + (size_t)row * DIMD);
        const float4* wp = (const float4*)(W + (size_t)k * DIMD);
        double s = 0.0;
        #pragma unroll
        for (int j = 0; j < 8; ++j) {
            const float4 x = xp[j * 16 + gl];
            const float4 w = wp[j * 16 + gl];
            s += (double)x.x * w.x + (double)x.y * w.y
               + (double)x.z * w.z + (double)x.w * w.w;
        }
        #pragma unroll
        for (int m = 1; m < 16; m <<= 1) s += __shfl_xor(s, m, 64);
        if (gl == 0) {
            const float Df = (float)s;
            const float dist = (xsq[row] + wsq[k]) - 2.0f * Df;
            const unsigned long long p =
                ((unsigned long long)__float_as_uint(dist) << 32) | (unsigned long long)k;
            atomicMin(res + row, p);
        }
    }
}

// ===================== outputs: gather (+ids, finish fused) + losses =====================
__global__ __launch_bounds__(256) void gather_k(const float* __restrict__ A,
                                                const float* __restrict__ W,
                                                const unsigned long long* __restrict__ res,
                                                float* __restrict__ out_zq,
                                                float* __restrict__ out_ids,
                                                double* __restrict__ partial)
{
    __shared__ double wsum[4];
    const int t   = threadIdx.x;
    const int row = blockIdx.x * 2 + (t >> 7);
    const int col = t & 127;
    const int id  = (int)(res[row] & 8191ull);
    if ((t & 127) == 0) out_ids[row] = (float)id;
    const float4 ze = ((const float4*)(A + (size_t)row * DIMD))[col];
    const float4 zq = ((const float4*)(W + (size_t)id  * DIMD))[col];
    float4 o;
    o.x = ze.x + (zq.x - ze.x);
    o.y = ze.y + (zq.y - ze.y);
    o.z = ze.z + (zq.z - ze.z);
    o.w = ze.w + (zq.w - ze.w);
    ((float4*)(out_zq + (size_t)row * DIMD))[col] = o;
    const float dx = zq.x - ze.x, dy = zq.y - ze.y, dz = zq.z - ze.z, dw = zq.w - ze.w;
    double s = (double)dx*dx + (double)dy*dy + (double)dz*dz + (double)dw*dw;
    #pragma unroll
    for (int m = 1; m < 64; m <<= 1) s += __shfl_xor(s, m, 64);
    if ((t & 63) == 0) wsum[t >> 6] = s;
    __syncthreads();
    if (t == 0) partial[blockIdx.x] = (wsum[0] + wsum[1]) + (wsum[2] + wsum[3]);
}

__global__ __launch_bounds__(256) void fin_k(const double* __restrict__ partial,
                                             float* __restrict__ outs)
{
    __shared__ double wsum[4];
    const int t = threadIdx.x;
    double s = 0.0;
    for (int i = 0; i < 32; ++i) s += partial[t + 256 * i];
    #pragma unroll
    for (int m = 1; m < 64; m <<= 1) s += __shfl_xor(s, m, 64);
    if ((t & 63) == 0) wsum[t >> 6] = s;
    __syncthreads();
    if (t == 0) {
        const double tot = (wsum[0] + wsum[1]) + (wsum[2] + wsum[3]);
        const double mse = tot / (double)((size_t)MROWS * DIMD);
        const float mf = (float)mse;
        const float vq = (float)(mse * 1.25);
        outs[0] = vq; outs[1] = mf; outs[2] = mf; outs[3] = 0.0f; outs[4] = vq;
    }
}

// ===================== launch =====================

extern "C" void kernel_launch(void* const* d_in, const int* in_sizes, int n_in,
                              void* d_out, int out_size, void* d_ws, size_t ws_size,
                              hipStream_t stream)
{
    const float* A = (const float*)d_in[0];
    const float* W = (const float*)d_in[1];

    char* ws = (char*)d_ws;
    unsigned char* A8  = (unsigned char*)(ws + OFF_A8);
    unsigned char* W8T = (unsigned char*)(ws + OFF_W8T);
    float*  xsq     = (float*)(ws + OFF_XSQ);
    float*  wsq     = (float*)(ws + OFF_WSQ);
    float*  rowthr  = (float*)(ws + OFF_THR);
    float*  partmin2= (float*)(ws + OFF_PM2);
    unsigned long long* res = (unsigned long long*)(ws + OFF_RES);
    unsigned int* ctcnt     = (unsigned int*)(ws + OFF_CTCNT);
    unsigned int* gcount    = (unsigned int*)(ws + OFF_GCNT);
    unsigned short* ctrows  = (unsigned short*)(ws + OFF_CTROWS);
    unsigned int* list      = (unsigned int*)(ws + OFF_LIST);
    double* partial = (double*)(ws + OFF_PARTIAL);

    float* out_zq  = (float*)d_out;
    float* out_ids = out_zq + (size_t)MROWS * DIMD;
    float* out_sc  = out_ids + MROWS;

    cvt2_k<<<2048, 256, 0, stream>>>(A, W, A8, W8T, xsq, wsq, ctcnt, gcount);
    minpass_k<<<1024, 256, 0, stream>>>(A8, W8T, partmin2);
    qualify_k<<<64, 256, 0, stream>>>(partmin2, rowthr, ctcnt, ctrows, res);
    cand_k<<<dim3(64, 128), 256, 0, stream>>>(A8, W8T, rowthr, ctcnt, ctrows, list, gcount);
    refine_k<<<2048, 256, 0, stream>>>(A, W, xsq, wsq, list, gcount, res);
    gather_k<<<8192, 256, 0, stream>>>(A, W, res, out_zq, out_ids, partial);
    fin_k<<<1, 256, 0, stream>>>(partial, out_sc);
}